// Round 9
// baseline (175.306 us; speedup 1.0000x reference)
//
#include <hip/hip_runtime.h>
#include <math.h>

#define CC 128
#define NL 16384
#define HH 64
#define WW 64

typedef __attribute__((ext_vector_type(8))) short short8;
typedef __attribute__((ext_vector_type(4))) float f32x4;

__device__ __forceinline__ unsigned short f2bf(float f) {
    union { float f; unsigned u; } v; v.f = f;
    unsigned r = v.u + 0x7fff + ((v.u >> 16) & 1);   // RNE
    return (unsigned short)(r >> 16);
}
__device__ __forceinline__ float bf2f(unsigned short u) {
    union { unsigned u; float f; } v; v.u = ((unsigned)u) << 16;
    return v.f;
}

// ---------------------------------------------------------------------------
// Fused DCN block: one kernel does  val(halo) -> om -> sample -> @Wo -> ybuf.
// Block = one h-row (64 w) of one image; val for rows h-2..h+2 lives in LDS.
// Valid because |offset| << 1 (Wom scaled 0.01): sample y in (h-2, h+2).
// valt uses an XOR swizzle (stride 256B is bank-aligned; swizzle spreads rows).
// ---------------------------------------------------------------------------
#define OFF_VALT 0          // bf16 [320][128] swizzled : 81920
#define OFF_BS   81920      // bf16 [128][136]          : 34816  (Wv -> Wom -> Wo)
#define OFF_AS   116736     // bf16 [64][136]           : 17408  (A_center -> sampled)
#define OFF_OM   134144     // f32  [64][108]           : 27648  (bnsc/bnsh overlay early)
#define OFF_LST  161792     // f32  [256]               : 1024
#define SMEM_TOT 162816     // <= 163840 (160 KiB)

template<int PASS>
__global__ __launch_bounds__(256) void fused_dcn_kernel(
    const float* __restrict__ in,      // PASS0: x NCHW ; PASS1: ybuf NHWC
    const float* __restrict__ Wv, const float* __restrict__ bv,
    const float* __restrict__ Wom, const float* __restrict__ bom,
    const float* __restrict__ Wo,
    const float* __restrict__ stats_in, const float* __restrict__ gamma,
    const float* __restrict__ beta,
    float* __restrict__ ybuf, float* __restrict__ stats_out)
{
    __shared__ __align__(16) char smem[SMEM_TOT];
    unsigned short* valt = (unsigned short*)(smem + OFF_VALT);
    unsigned short* Bs   = (unsigned short*)(smem + OFF_BS);
    unsigned short* As   = (unsigned short*)(smem + OFF_AS);
    float* omtile = (float*)(smem + OFF_OM);
    float* bnsc   = (float*)(smem + OFF_OM);     // overlay: dead before omtile written
    float* bnsh   = bnsc + 128;
    float* lstat  = (float*)(smem + OFF_LST);

    const int tid = threadIdx.x;
    const int bid = blockIdx.x;
    const int block_m = bid * 64;
    const int n_img = block_m >> 12;
    const int h     = (block_m & 4095) >> 6;

    const int w  = tid >> 6;
    const int l  = tid & 63;
    const int lr = l & 15;
    const int lk = l >> 4;

    lstat[tid] = 0.0f;

    if (PASS == 1) {
        if (tid < 128) {
            float s = 0.f, sq = 0.f;
#pragma unroll
            for (int g = 0; g < 8; g++) {
                s  += stats_in[g * 256 + tid];
                sq += stats_in[g * 256 + 128 + tid];
            }
            const float inv = 1.0f / 16384.0f;
            float mean = s * inv;
            float var  = sq * inv - mean * mean;
            float sc   = rsqrtf(var + 1e-5f) * gamma[tid];
            bnsc[tid] = sc;
            bnsh[tid] = beta[tid] - mean * sc;
        }
        __syncthreads();
    }

    // ---- Bs <- Wv^T (transpose-convert fp32->bf16) ----
#pragma unroll
    for (int i = 0; i < 16; i++) {
        int id = tid + i * 256;
        int k = id >> 5, n4 = (id & 31) * 4;
        float4 v = *(const float4*)(Wv + (size_t)k * CC + n4);
        Bs[(n4 + 0) * 136 + k] = f2bf(v.x);
        Bs[(n4 + 1) * 136 + k] = f2bf(v.y);
        Bs[(n4 + 2) * 136 + k] = f2bf(v.z);
        Bs[(n4 + 3) * 136 + k] = f2bf(v.w);
    }

    // ---- val halo: 5 chunks, center (hh=2) LAST so As keeps A_center ----
    const int order[5] = {0, 1, 3, 4, 2};
#pragma unroll
    for (int ci = 0; ci < 5; ci++) {
        int hh = order[ci];
        int hsrc = min(max(h - 2 + hh, 0), HH - 1);
        // stage As (64 rows x 128 c)
        if (PASS == 0) {
#pragma unroll
            for (int i = 0; i < 8; i++) {
                int id = tid + i * 256;
                int c = id >> 4, j4 = id & 15;
                float4 v = *(const float4*)(in + (((size_t)(n_img * CC + c)) << 12) + hsrc * WW + j4 * 4);
                As[(j4 * 4 + 0) * 136 + c] = f2bf(v.x);
                As[(j4 * 4 + 1) * 136 + c] = f2bf(v.y);
                As[(j4 * 4 + 2) * 136 + c] = f2bf(v.z);
                As[(j4 * 4 + 3) * 136 + c] = f2bf(v.w);
            }
        } else {
            size_t nlb = ((size_t)n_img << 12) + (size_t)hsrc * WW;
#pragma unroll
            for (int i = 0; i < 8; i++) {
                int id = tid + i * 256;
                int r = id >> 5, c = (id & 31) * 4;
                float4 v = *(const float4*)(in + (nlb + r) * CC + c);
                As[r * 136 + c + 0] = f2bf(fmaxf(v.x * bnsc[c + 0] + bnsh[c + 0], 0.f));
                As[r * 136 + c + 1] = f2bf(fmaxf(v.y * bnsc[c + 1] + bnsh[c + 1], 0.f));
                As[r * 136 + c + 2] = f2bf(fmaxf(v.z * bnsc[c + 2] + bnsh[c + 2], 0.f));
                As[r * 136 + c + 3] = f2bf(fmaxf(v.w * bnsc[c + 3] + bnsh[c + 3], 0.f));
            }
        }
        __syncthreads();                         // As (and on ci==0, Bs) ready

        f32x4 acc[8];
#pragma unroll
        for (int j = 0; j < 8; j++) acc[j] = (f32x4){0.f, 0.f, 0.f, 0.f};
#pragma unroll
        for (int kk = 0; kk < 4; kk++) {
            short8 a = *(const short8*)(&As[(w * 16 + lr) * 136 + kk * 32 + lk * 8]);
#pragma unroll
            for (int j = 0; j < 8; j++) {
                short8 b = *(const short8*)(&Bs[(j * 16 + lr) * 136 + kk * 32 + lk * 8]);
                acc[j] = __builtin_amdgcn_mfma_f32_16x16x32_bf16(a, b, acc[j], 0, 0, 0);
            }
        }
        int rbase = hh * 64 + w * 16 + lk * 4;
#pragma unroll
        for (int j = 0; j < 8; j++) {
            int c = j * 16 + lr;
            float bb = bv[c];
#pragma unroll
            for (int rr = 0; rr < 4; rr++) {
                int vrow = rbase + rr;
                int idx = vrow * 128 + (((c >> 3) ^ (vrow & 7)) * 8) + (c & 7);
                valt[idx] = f2bf(acc[j][rr] + bb);
            }
        }
        __syncthreads();                         // valt chunk done; As reusable
    }

    // ---- Bs <- Wom^T (rows 0..107; 108..111 zero) ----
    if (tid < 68) {
        int r = 108 + tid / 17, q = tid % 17;
        float4 z; z.x = 0.f; z.y = 0.f; z.z = 0.f; z.w = 0.f;
        *(float4*)(&Bs[r * 136 + q * 8]) = z;
    }
#pragma unroll
    for (int i = 0; i < 14; i++) {
        int id = tid + i * 256;
        if (id < 3456) {
            int k = id / 27, q = id - k * 27;
            float4 v = *(const float4*)(Wom + (size_t)k * 108 + q * 4);
            Bs[(q * 4 + 0) * 136 + k] = f2bf(v.x);
            Bs[(q * 4 + 1) * 136 + k] = f2bf(v.y);
            Bs[(q * 4 + 2) * 136 + k] = f2bf(v.z);
            Bs[(q * 4 + 3) * 136 + k] = f2bf(v.w);
        }
    }
    __syncthreads();

    // ---- omtile = A_center @ Wom + bom (fp32, LDS) ----
    {
        f32x4 acc[7];
#pragma unroll
        for (int j = 0; j < 7; j++) acc[j] = (f32x4){0.f, 0.f, 0.f, 0.f};
#pragma unroll
        for (int kk = 0; kk < 4; kk++) {
            short8 a = *(const short8*)(&As[(w * 16 + lr) * 136 + kk * 32 + lk * 8]);
#pragma unroll
            for (int j = 0; j < 7; j++) {
                short8 b = *(const short8*)(&Bs[(j * 16 + lr) * 136 + kk * 32 + lk * 8]);
                acc[j] = __builtin_amdgcn_mfma_f32_16x16x32_bf16(a, b, acc[j], 0, 0, 0);
            }
        }
        int row0 = w * 16 + lk * 4;
#pragma unroll
        for (int j = 0; j < 7; j++) {
            int col = j * 16 + lr;
            if (col < 108) {
                float bb = bom[col];
#pragma unroll
                for (int rr = 0; rr < 4; rr++)
                    omtile[(row0 + rr) * 108 + col] = acc[j][rr] + bb;
            }
        }
    }
    __syncthreads();                             // omtile ready; Bs (Wom) dead

    // ---- Bs <- Wo^T (latency hidden under sampler) ----
#pragma unroll
    for (int i = 0; i < 16; i++) {
        int id = tid + i * 256;
        int k = id >> 5, n4 = (id & 31) * 4;
        float4 v = *(const float4*)(Wo + (size_t)k * CC + n4);
        Bs[(n4 + 0) * 136 + k] = f2bf(v.x);
        Bs[(n4 + 1) * 136 + k] = f2bf(v.y);
        Bs[(n4 + 2) * 136 + k] = f2bf(v.z);
        Bs[(n4 + 3) * 136 + k] = f2bf(v.w);
    }

    // ---- sample from valt (LDS) -> As (overwrites A_center) ----
#pragma unroll
    for (int it = 0; it < 4; it++) {
        int lane_id = tid + it * 256;            // 0..1023
        int unit = lane_id >> 2;                 // r*4+g
        int l4 = lane_id & 3;
        int r = unit >> 2;                       // w position 0..63
        int g = unit & 3;
        const float* omr = omtile + r * 108 + g * 27;
        int cg = g * 4 + l4;

        float av[8];
#pragma unroll
        for (int q = 0; q < 8; q++) av[q] = 0.f;
#pragma unroll
        for (int k = 0; k < 9; k++) {
            float ox = omr[2 * k];
            float oy = omr[2 * k + 1];
            float mk = omr[18 + k];
            float ly = (float)(h + k / 3 - 1) + oy;
            float lx = (float)(r + k % 3 - 1) + ox;
            float y0f = floorf(ly), x0f = floorf(lx);
            float wy = ly - y0f, wx = lx - x0f;
            int y0 = (int)y0f, x0 = (int)x0f;
#pragma unroll
            for (int cy = 0; cy < 2; cy++) {
#pragma unroll
                for (int cx = 0; cx < 2; cx++) {
                    int yi = y0 + cy, xi = x0 + cx;
                    float wgt = (cy ? wy : 1.f - wy) * (cx ? wx : 1.f - wx);
                    bool valid = (yi >= 0) && (yi < HH) && (xi >= 0) && (xi < WW);
                    wgt = mk * (valid ? wgt : 0.f);
                    int yc = min(max(yi, 0), HH - 1);
                    int xc = min(max(xi, 0), WW - 1);
                    int ylocal = min(max(yc - h + 2, 0), 4);   // safety clamp
                    int vrow = ylocal * 64 + xc;
                    int idx = vrow * 128 + ((cg ^ (vrow & 7)) * 8);
                    uint4 pv = *(const uint4*)(&valt[idx]);
                    unsigned pw[4] = {pv.x, pv.y, pv.z, pv.w};
#pragma unroll
                    for (int q = 0; q < 4; q++) {
                        av[2 * q + 0] += bf2f((unsigned short)(pw[q] & 0xffff)) * wgt;
                        av[2 * q + 1] += bf2f((unsigned short)(pw[q] >> 16)) * wgt;
                    }
                }
            }
        }
        unsigned p0 = (unsigned)f2bf(av[0]) | ((unsigned)f2bf(av[1]) << 16);
        unsigned p1 = (unsigned)f2bf(av[2]) | ((unsigned)f2bf(av[3]) << 16);
        unsigned p2 = (unsigned)f2bf(av[4]) | ((unsigned)f2bf(av[5]) << 16);
        unsigned p3 = (unsigned)f2bf(av[6]) | ((unsigned)f2bf(av[7]) << 16);
        uint4 pk; pk.x = p0; pk.y = p1; pk.z = p2; pk.w = p3;
        *(uint4*)(&As[r * 136 + g * 32 + l4 * 8]) = pk;
    }
    __syncthreads();                             // sampled + Wo ready

    // ---- ybuf = sampled @ Wo ; BN stats ----
    {
        f32x4 acc[8];
#pragma unroll
        for (int j = 0; j < 8; j++) acc[j] = (f32x4){0.f, 0.f, 0.f, 0.f};
#pragma unroll
        for (int kk = 0; kk < 4; kk++) {
            short8 a = *(const short8*)(&As[(w * 16 + lr) * 136 + kk * 32 + lk * 8]);
#pragma unroll
            for (int j = 0; j < 8; j++) {
                short8 b = *(const short8*)(&Bs[(j * 16 + lr) * 136 + kk * 32 + lk * 8]);
                acc[j] = __builtin_amdgcn_mfma_f32_16x16x32_bf16(a, b, acc[j], 0, 0, 0);
            }
        }
        int row0 = block_m + w * 16 + lk * 4;
#pragma unroll
        for (int j = 0; j < 8; j++) {
            int col = j * 16 + lr;
            float s = 0.f, sq = 0.f;
#pragma unroll
            for (int rr = 0; rr < 4; rr++) {
                float v = acc[j][rr];
                ybuf[(size_t)(row0 + rr) * CC + col] = v;
                s += v;
                sq += v * v;
            }
            atomicAdd(&lstat[col], s);
            atomicAdd(&lstat[128 + col], sq);
        }
    }
    __syncthreads();
    if (tid < 128) {
        float* sg = stats_out + (bid & 7) * 256;
        atomicAdd(&sg[tid], lstat[tid]);
        atomicAdd(&sg[128 + tid], lstat[128 + tid]);
    }
}

// ---------------------------------------------------------------------------
// final: A = bn(ybuf) + x (NCHW residual), B = Wc; out NCHW fp32.
// ---------------------------------------------------------------------------
__global__ __launch_bounds__(256) void gemm_final_kernel(
    const float* __restrict__ ybuf, const float* __restrict__ x,
    const float* __restrict__ Wc, const float* __restrict__ stats_in,
    const float* __restrict__ gamma, const float* __restrict__ beta,
    float* __restrict__ out)
{
    __shared__ unsigned short As[64 * 136];
    __shared__ unsigned short Bs[128 * 136];
    __shared__ float Xs[64 * 129];
    __shared__ float bnsc[128], bnsh[128];
    float* Tt = (float*)Bs;                      // reused post-MFMA

    const int tid = threadIdx.x;
    const int block_m = blockIdx.x * 64;
    const int n_img = block_m >> 12;
    const int hw0 = block_m & 4095;

    if (tid < 128) {
        float s = 0.f, sq = 0.f;
#pragma unroll
        for (int g = 0; g < 8; g++) {
            s  += stats_in[g * 256 + tid];
            sq += stats_in[g * 256 + 128 + tid];
        }
        const float inv = 1.0f / 16384.0f;
        float mean = s * inv;
        float var  = sq * inv - mean * mean;
        float sc   = rsqrtf(var + 1e-5f) * gamma[tid];
        bnsc[tid] = sc;
        bnsh[tid] = beta[tid] - mean * sc;
    }
#pragma unroll
    for (int i = 0; i < 8; i++) {
        int id = tid + i * 256;
        int c = id >> 4, j4 = id & 15;
        float4 v = *(const float4*)(x + (((size_t)(n_img * CC + c)) << 12) + hw0 + j4 * 4);
        Xs[(j4 * 4 + 0) * 129 + c] = v.x;
        Xs[(j4 * 4 + 1) * 129 + c] = v.y;
        Xs[(j4 * 4 + 2) * 129 + c] = v.z;
        Xs[(j4 * 4 + 3) * 129 + c] = v.w;
    }
#pragma unroll
    for (int i = 0; i < 16; i++) {
        int id = tid + i * 256;
        int r = id >> 5, c4 = (id & 31) * 4;
        float4 v = *(const float4*)(Wc + (size_t)r * CC + c4);
        Bs[r * 136 + c4 + 0] = f2bf(v.x);
        Bs[r * 136 + c4 + 1] = f2bf(v.y);
        Bs[r * 136 + c4 + 2] = f2bf(v.z);
        Bs[r * 136 + c4 + 3] = f2bf(v.w);
    }
    __syncthreads();
#pragma unroll
    for (int i = 0; i < 8; i++) {
        int id = tid + i * 256;
        int r = id >> 5, c = (id & 31) * 4;
        float4 yv = *(const float4*)(ybuf + (size_t)(block_m + r) * CC + c);
        As[r * 136 + c + 0] = f2bf(yv.x * bnsc[c + 0] + bnsh[c + 0] + Xs[r * 129 + c + 0]);
        As[r * 136 + c + 1] = f2bf(yv.y * bnsc[c + 1] + bnsh[c + 1] + Xs[r * 129 + c + 1]);
        As[r * 136 + c + 2] = f2bf(yv.z * bnsc[c + 2] + bnsh[c + 2] + Xs[r * 129 + c + 2]);
        As[r * 136 + c + 3] = f2bf(yv.w * bnsc[c + 3] + bnsh[c + 3] + Xs[r * 129 + c + 3]);
    }
    __syncthreads();

    const int w  = tid >> 6;
    const int l  = tid & 63;
    const int lr = l & 15;
    const int lk = l >> 4;
    {
        f32x4 acc[8];
#pragma unroll
        for (int j = 0; j < 8; j++) acc[j] = (f32x4){0.f, 0.f, 0.f, 0.f};
#pragma unroll
        for (int kk = 0; kk < 4; kk++) {
            short8 a = *(const short8*)(&As[(w * 16 + lr) * 136 + kk * 32 + lk * 8]);
#pragma unroll
            for (int j = 0; j < 8; j++) {
                short8 b = *(const short8*)(&Bs[(j * 16 + lr) * 136 + kk * 32 + lk * 8]);
                acc[j] = __builtin_amdgcn_mfma_f32_16x16x32_bf16(a, b, acc[j], 0, 0, 0);
            }
        }
        __syncthreads();
        int row0 = w * 16 + lk * 4;
#pragma unroll
        for (int j = 0; j < 8; j++) {
            int col = j * 16 + lr;
#pragma unroll
            for (int rr = 0; rr < 4; rr++)
                Tt[col * 68 + row0 + rr] = acc[j][rr];
        }
    }
    __syncthreads();
#pragma unroll
    for (int i = 0; i < 8; i++) {
        int id = tid + i * 256;
        int o = id >> 4, j4 = id & 15;
        float4 v = *(const float4*)(&Tt[o * 68 + j4 * 4]);
        *(float4*)(out + (((size_t)(n_img * CC + o)) << 12) + hw0 + j4 * 4) = v;
    }
}

// ---------------------------------------------------------------------------
extern "C" void kernel_launch(void* const* d_in, const int* in_sizes, int n_in,
                              void* d_out, int out_size, void* d_ws, size_t ws_size,
                              hipStream_t stream)
{
    (void)in_sizes; (void)n_in; (void)out_size; (void)ws_size;
    const float* x     = (const float*)d_in[0];
    const float* Wv    = (const float*)d_in[1];
    const float* bv    = (const float*)d_in[2];
    const float* Wom   = (const float*)d_in[3];
    const float* bom   = (const float*)d_in[4];
    const float* Wo    = (const float*)d_in[5];
    const float* gamma = (const float*)d_in[6];
    const float* beta  = (const float*)d_in[7];
    const float* Wc    = (const float*)d_in[8];
    float* out = (float*)d_out;

    char* ws = (char*)d_ws;
    float* ybuf  = (float*)ws;   ws += (size_t)NL * CC * 4;   // 8 MB
    float* stats = (float*)ws;   ws += 4096 * 4;              // 2 sets x 8 groups x 256

    hipMemsetAsync(stats, 0, 4096 * 4, stream);

    dim3 b256(256);
    fused_dcn_kernel<0><<<256, b256, 0, stream>>>(x, Wv, bv, Wom, bom, Wo,
                                                  nullptr, gamma, beta, ybuf, stats);
    fused_dcn_kernel<1><<<256, b256, 0, stream>>>(ybuf, Wv, bv, Wom, bom, Wo,
                                                  stats, gamma, beta, ybuf, stats + 2048);
    gemm_final_kernel<<<256, b256, 0, stream>>>(ybuf, x, Wc, stats + 2048, gamma, beta, out);
}